// Round 4
// baseline (424.302 us; speedup 1.0000x reference)
//
#include <hip/hip_runtime.h>
#include <hip/hip_cooperative_groups.h>

namespace cg = cooperative_groups;

#define EPSF 1e-10f

constexpr int B = 32, K = 4, M = 3;
constexpr int NPIX = 256 * 256;
constexpr int BPB = 32;            // blocks per b -> 1024 blocks = 4/CU (cooperative-resident)
constexpr int THREADS = 256;
constexpr int WAVES = THREADS / 64;
constexpr int PXB = NPIX / BPB;    // 2048 px per block
constexpr int CHUNKS = PXB / (THREADS * 4);  // 2
constexpr int NVALS = 1 + K + 2 * K * M;     // 29
constexpr int PSTRIDE = 32;

// ws float layout
constexpr int OFF_P1 = 0;                        // [B*BPB*PSTRIDE] pass1 partials
constexpr int OFF_LLP = OFF_P1 + B * BPB * PSTRIDE; // [B*BPB] pass2 partials
constexpr int OFF_N  = OFF_LLP + B * BPB;        // [B]
// fallback-path extra params
constexpr int OFF_ALPHA = OFF_N + B;             // [B*K]
constexpr int OFF_MU    = OFF_ALPHA + B * K;     // [B*K*M]
constexpr int OFF_IV    = OFF_MU + B * K * M;    // [B*K*M]
constexpr int OFF_CST   = OFF_IV + B * K * M;    // [B*K]

__device__ __forceinline__ float wave_reduce(float v) {
    #pragma unroll
    for (int off = 32; off > 0; off >>= 1) v += __shfl_down(v, off, 64);
    return v;
}

// ---------------------------------------------------------------- fused (cooperative)
__global__ __launch_bounds__(THREADS, 4) void fused_kernel(
    const float* __restrict__ pred, const float* __restrict__ xin,
    const int* __restrict__ heart, float* __restrict__ ws, float* __restrict__ out) {
    __shared__ float xs[M][PXB];       // 24 KB: inputs slice cached for pass2
    __shared__ float msk[PXB];         // 8 KB: mask slice
    __shared__ float red[WAVES * NVALS];
    __shared__ float par[K * 8];       // per-k: alpha,cst,mu[3],iv[3]

    const int b  = blockIdx.x / BPB;
    const int cb = blockIdx.x % BPB;
    const int tid = threadIdx.x;

    // ---- pass 1: global sweep, stash xin+mask in LDS, reduce 29 partials
    float nacc = 0.0f;
    float Wk[K] = {};
    float Pa[K][M] = {};
    float Qa[K][M] = {};

    #pragma unroll
    for (int it = 0; it < CHUNKS; ++it) {
        const int li = (it * THREADS + tid) * 4;   // local px in [0,2048)
        const int p0 = cb * PXB + li;              // px within this b

        const int4 h4 = *(const int4*)(heart + b * NPIX + p0);
        float mk[4];
        mk[0] = (h4.x == 1) ? 1.0f : 0.0f;
        mk[1] = (h4.y == 1) ? 1.0f : 0.0f;
        mk[2] = (h4.z == 1) ? 1.0f : 0.0f;
        mk[3] = (h4.w == 1) ? 1.0f : 0.0f;
        *(float4*)&msk[li] = make_float4(mk[0], mk[1], mk[2], mk[3]);
        nacc += (mk[0] + mk[1]) + (mk[2] + mk[3]);

        float xv[M][4];
        #pragma unroll
        for (int m = 0; m < M; ++m) {
            float4 t = *(const float4*)(xin + (b * M + m) * NPIX + p0);
            *(float4*)&xs[m][li] = t;
            xv[m][0] = t.x; xv[m][1] = t.y; xv[m][2] = t.z; xv[m][3] = t.w;
        }

        #pragma unroll
        for (int k = 0; k < K; ++k) {
            float4 pr = *(const float4*)(pred + (b * K + k) * NPIX + p0);
            float pm[4];
            pm[0] = pr.x * mk[0]; pm[1] = pr.y * mk[1];
            pm[2] = pr.z * mk[2]; pm[3] = pr.w * mk[3];
            Wk[k] += (pm[0] + pm[1]) + (pm[2] + pm[3]);
            #pragma unroll
            for (int m = 0; m < M; ++m) {
                #pragma unroll
                for (int j = 0; j < 4; ++j) {
                    float px = pm[j] * xv[m][j];
                    Pa[k][m] += px;
                    Qa[k][m] += px * xv[m][j];
                }
            }
        }
    }

    float vals[NVALS];
    vals[0] = nacc;
    #pragma unroll
    for (int k = 0; k < K; ++k) vals[1 + k] = Wk[k];
    #pragma unroll
    for (int k = 0; k < K; ++k)
        #pragma unroll
        for (int m = 0; m < M; ++m) {
            vals[1 + K + k * M + m]         = Pa[k][m];
            vals[1 + K + K * M + k * M + m] = Qa[k][m];
        }
    #pragma unroll
    for (int i = 0; i < NVALS; ++i) vals[i] = wave_reduce(vals[i]);
    const int wave = tid >> 6;
    if ((tid & 63) == 0) {
        #pragma unroll
        for (int i = 0; i < NVALS; ++i) red[wave * NVALS + i] = vals[i];
    }
    __syncthreads();
    if (tid < NVALS) {
        float s = red[tid];
        #pragma unroll
        for (int w = 1; w < WAVES; ++w) s += red[w * NVALS + tid];
        ws[OFF_P1 + (b * BPB + cb) * PSTRIDE + tid] = s;
    }
    __threadfence();
    cg::this_grid().sync();

    // ---- params: every block computes its b's params from the 32 partial rows
    if (tid < K) {
        const int k = tid;
        float n = 0.0f, W = 0.0f, P[M] = {}, Q[M] = {};
        for (int p = 0; p < BPB; ++p) {
            const float* base = ws + OFF_P1 + (b * BPB + p) * PSTRIDE;
            n += base[0];
            W += base[1 + k];
            #pragma unroll
            for (int m = 0; m < M; ++m) {
                P[m] += base[1 + K + k * M + m];
                Q[m] += base[1 + K + K * M + k * M + m];
            }
        }
        const float s = W + EPSF;
        par[k * 8 + 0] = W / n;
        float cst = 0.0f;
        #pragma unroll
        for (int m = 0; m < M; ++m) {
            const float mu = P[m] / s;
            const float var = (Q[m] - 2.0f * mu * P[m] + mu * mu * W) / s + EPSF;
            par[k * 8 + 2 + m] = mu;
            par[k * 8 + 5 + m] = 0.5f / var;
            cst -= 0.5f * logf(6.2831853071795864f * var);
        }
        par[k * 8 + 1] = cst;
        if (k == 0 && cb == 0) ws[OFF_N + b] = n;
    }
    __syncthreads();

    // ---- pass 2: entirely from LDS
    float alpha[K], cst[K], mu[K][M], iv[K][M];
    #pragma unroll
    for (int k = 0; k < K; ++k) {
        alpha[k] = par[k * 8 + 0];
        cst[k]   = par[k * 8 + 1];
        #pragma unroll
        for (int m = 0; m < M; ++m) {
            mu[k][m] = par[k * 8 + 2 + m];
            iv[k][m] = par[k * 8 + 5 + m];
        }
    }

    float acc = 0.0f;
    #pragma unroll
    for (int it = 0; it < CHUNKS; ++it) {
        const int li = (it * THREADS + tid) * 4;
        const float4 mk4 = *(const float4*)&msk[li];
        const float mk[4] = {mk4.x, mk4.y, mk4.z, mk4.w};
        float xv[M][4];
        #pragma unroll
        for (int m = 0; m < M; ++m) {
            float4 t = *(const float4*)&xs[m][li];
            xv[m][0] = t.x; xv[m][1] = t.y; xv[m][2] = t.z; xv[m][3] = t.w;
        }
        #pragma unroll
        for (int j = 0; j < 4; ++j) {
            float mix = EPSF;
            #pragma unroll
            for (int k = 0; k < K; ++k) {
                float lp = cst[k];
                #pragma unroll
                for (int m = 0; m < M; ++m) {
                    float d = xv[m][j] - mu[k][m];
                    lp -= d * d * iv[k][m];
                }
                mix += alpha[k] * __expf(lp);
            }
            acc += mk[j] * __logf(mix);
        }
    }

    __syncthreads();          // red[] reuse
    acc = wave_reduce(acc);
    if ((tid & 63) == 0) red[wave] = acc;
    __syncthreads();
    if (tid == 0) {
        float s2 = red[0];
        #pragma unroll
        for (int w = 1; w < WAVES; ++w) s2 += red[w];
        ws[OFF_LLP + b * BPB + cb] = s2;
    }
    __threadfence();
    cg::this_grid().sync();

    // ---- final: block 0, first wave
    if (blockIdx.x == 0 && tid < 64) {
        float val = 0.0f;
        if (tid < B) {
            float s = 0.0f;
            for (int p = 0; p < BPB; ++p) s += ws[OFF_LLP + tid * BPB + p];
            val = -s / ws[OFF_N + tid];
        }
        val = wave_reduce(val);
        if (tid == 0) out[0] = val / (float)B;
    }
}

// ---------------------------------------------------------------- fallback (R3 path)
__global__ __launch_bounds__(THREADS) void pass1_kernel(
    const float* __restrict__ pred, const float* __restrict__ xin,
    const int* __restrict__ heart, float* __restrict__ ws) {
    const int b  = blockIdx.x / BPB;
    const int cb = blockIdx.x % BPB;
    float nacc = 0.0f;
    float Wk[K] = {};
    float Pa[K][M] = {};
    float Qa[K][M] = {};
    #pragma unroll
    for (int it = 0; it < CHUNKS; ++it) {
        const int p0 = cb * PXB + (it * THREADS + threadIdx.x) * 4;
        const int4 h4 = *(const int4*)(heart + b * NPIX + p0);
        float mk[4];
        mk[0] = (h4.x == 1) ? 1.0f : 0.0f;
        mk[1] = (h4.y == 1) ? 1.0f : 0.0f;
        mk[2] = (h4.z == 1) ? 1.0f : 0.0f;
        mk[3] = (h4.w == 1) ? 1.0f : 0.0f;
        nacc += (mk[0] + mk[1]) + (mk[2] + mk[3]);
        float xv[M][4];
        #pragma unroll
        for (int m = 0; m < M; ++m) {
            float4 t = *(const float4*)(xin + (b * M + m) * NPIX + p0);
            xv[m][0] = t.x; xv[m][1] = t.y; xv[m][2] = t.z; xv[m][3] = t.w;
        }
        #pragma unroll
        for (int k = 0; k < K; ++k) {
            float4 pr = *(const float4*)(pred + (b * K + k) * NPIX + p0);
            float pm[4];
            pm[0] = pr.x * mk[0]; pm[1] = pr.y * mk[1];
            pm[2] = pr.z * mk[2]; pm[3] = pr.w * mk[3];
            Wk[k] += (pm[0] + pm[1]) + (pm[2] + pm[3]);
            #pragma unroll
            for (int m = 0; m < M; ++m)
                #pragma unroll
                for (int j = 0; j < 4; ++j) {
                    float px = pm[j] * xv[m][j];
                    Pa[k][m] += px;
                    Qa[k][m] += px * xv[m][j];
                }
        }
    }
    float vals[NVALS];
    vals[0] = nacc;
    #pragma unroll
    for (int k = 0; k < K; ++k) vals[1 + k] = Wk[k];
    #pragma unroll
    for (int k = 0; k < K; ++k)
        #pragma unroll
        for (int m = 0; m < M; ++m) {
            vals[1 + K + k * M + m]         = Pa[k][m];
            vals[1 + K + K * M + k * M + m] = Qa[k][m];
        }
    __shared__ float red[WAVES * NVALS];
    #pragma unroll
    for (int i = 0; i < NVALS; ++i) vals[i] = wave_reduce(vals[i]);
    const int wave = threadIdx.x >> 6;
    if ((threadIdx.x & 63) == 0) {
        #pragma unroll
        for (int i = 0; i < NVALS; ++i) red[wave * NVALS + i] = vals[i];
    }
    __syncthreads();
    if (threadIdx.x < NVALS) {
        float s = red[threadIdx.x];
        #pragma unroll
        for (int w = 1; w < WAVES; ++w) s += red[w * NVALS + threadIdx.x];
        ws[OFF_P1 + (b * BPB + cb) * PSTRIDE + threadIdx.x] = s;
    }
}

__global__ __launch_bounds__(B * K) void params_kernel(float* __restrict__ ws) {
    const int t = threadIdx.x;
    const int b = t / K;
    const int k = t % K;
    float n = 0.0f, W = 0.0f, P[M] = {}, Q[M] = {};
    for (int p = 0; p < BPB; ++p) {
        const float* base = ws + OFF_P1 + (b * BPB + p) * PSTRIDE;
        n += base[0];
        W += base[1 + k];
        #pragma unroll
        for (int m = 0; m < M; ++m) {
            P[m] += base[1 + K + k * M + m];
            Q[m] += base[1 + K + K * M + k * M + m];
        }
    }
    const float s = W + EPSF;
    ws[OFF_ALPHA + t] = W / n;
    if (k == 0) ws[OFF_N + b] = n;
    float cst = 0.0f;
    #pragma unroll
    for (int m = 0; m < M; ++m) {
        const float mu = P[m] / s;
        const float var = (Q[m] - 2.0f * mu * P[m] + mu * mu * W) / s + EPSF;
        ws[OFF_MU + t * M + m] = mu;
        ws[OFF_IV + t * M + m] = 0.5f / var;
        cst -= 0.5f * logf(6.2831853071795864f * var);
    }
    ws[OFF_CST + t] = cst;
}

__global__ __launch_bounds__(THREADS) void pass2_kernel(
    const float* __restrict__ xin, const int* __restrict__ heart,
    float* __restrict__ ws) {
    const int b  = blockIdx.x / BPB;
    const int cb = blockIdx.x % BPB;
    float alpha[K], cst[K], mu[K][M], iv[K][M];
    #pragma unroll
    for (int k = 0; k < K; ++k) {
        alpha[k] = ws[OFF_ALPHA + b * K + k];
        cst[k]   = ws[OFF_CST + b * K + k];
        #pragma unroll
        for (int m = 0; m < M; ++m) {
            mu[k][m] = ws[OFF_MU + (b * K + k) * M + m];
            iv[k][m] = ws[OFF_IV + (b * K + k) * M + m];
        }
    }
    float acc = 0.0f;
    #pragma unroll
    for (int it = 0; it < CHUNKS; ++it) {
        const int p0 = cb * PXB + (it * THREADS + threadIdx.x) * 4;
        const int4 h4 = *(const int4*)(heart + b * NPIX + p0);
        int hv[4] = {h4.x, h4.y, h4.z, h4.w};
        float xv[M][4];
        #pragma unroll
        for (int m = 0; m < M; ++m) {
            float4 t = *(const float4*)(xin + (b * M + m) * NPIX + p0);
            xv[m][0] = t.x; xv[m][1] = t.y; xv[m][2] = t.z; xv[m][3] = t.w;
        }
        #pragma unroll
        for (int j = 0; j < 4; ++j) {
            float mix = EPSF;
            #pragma unroll
            for (int k = 0; k < K; ++k) {
                float lp = cst[k];
                #pragma unroll
                for (int m = 0; m < M; ++m) {
                    float d = xv[m][j] - mu[k][m];
                    lp -= d * d * iv[k][m];
                }
                mix += alpha[k] * __expf(lp);
            }
            acc += ((hv[j] == 1) ? 1.0f : 0.0f) * __logf(mix);
        }
    }
    __shared__ float red[WAVES];
    acc = wave_reduce(acc);
    const int wave = threadIdx.x >> 6;
    if ((threadIdx.x & 63) == 0) red[wave] = acc;
    __syncthreads();
    if (threadIdx.x == 0) {
        float s = red[0];
        #pragma unroll
        for (int w = 1; w < WAVES; ++w) s += red[w];
        ws[OFF_LLP + b * BPB + cb] = s;
    }
}

__global__ __launch_bounds__(64) void final_kernel(const float* __restrict__ ws,
                                                   float* __restrict__ out) {
    const int t = threadIdx.x;
    float val = 0.0f;
    if (t < B) {
        float s = 0.0f;
        for (int p = 0; p < BPB; ++p) s += ws[OFF_LLP + t * BPB + p];
        val = -s / ws[OFF_N + t];
    }
    val = wave_reduce(val);
    if (t == 0) out[0] = val / (float)B;
}

extern "C" void kernel_launch(void* const* d_in, const int* in_sizes, int n_in,
                              void* d_out, int out_size, void* d_ws, size_t ws_size,
                              hipStream_t stream) {
    const float* pred  = (const float*)d_in[0];
    const float* xin   = (const float*)d_in[1];
    const int*   heart = (const int*)d_in[2];
    float* out = (float*)d_out;
    float* ws  = (float*)d_ws;

    void* args[] = {(void*)&pred, (void*)&xin, (void*)&heart, (void*)&ws, (void*)&out};
    hipError_t e = hipLaunchCooperativeKernel((const void*)fused_kernel,
                                              dim3(B * BPB), dim3(THREADS),
                                              args, 0, stream);
    if (e != hipSuccess) {
        (void)hipGetLastError();  // clear sticky error, use fallback path
        pass1_kernel<<<B * BPB, THREADS, 0, stream>>>(pred, xin, heart, ws);
        params_kernel<<<1, B * K, 0, stream>>>(ws);
        pass2_kernel<<<B * BPB, THREADS, 0, stream>>>(xin, heart, ws);
        final_kernel<<<1, 64, 0, stream>>>(ws, out);
    }
}

// Round 5
// 303.730 us; speedup vs baseline: 1.3970x; 1.3970x over previous
//
#include <hip/hip_runtime.h>

#define EPSF 1e-10f

constexpr int B = 32, K = 4, M = 3;
constexpr int NPIX = 256 * 256;
constexpr int BPB = 32;            // blocks per b -> 1024 blocks = exactly 4/CU co-resident
constexpr int THREADS = 256;
constexpr int WAVES = THREADS / 64;
constexpr int PXB = NPIX / BPB;    // 2048 px per block
constexpr int CHUNKS = PXB / (THREADS * 4);  // 2
constexpr int NVALS = 1 + K + 2 * K * M;     // 29
constexpr int PSTRIDE = 32;

// ---- ws layout: 512-byte int header (counters/flags, zeroed by memset), then floats
// ints: [0..31]=arrive cnt per b, [32]=done cnt, [40..71]=param-ready flag per b
constexpr int HDR_BYTES = 512;
constexpr int OFF_P1  = 0;                       // [B*BPB*PSTRIDE] pass1 partials
constexpr int OFF_LLP = OFF_P1 + B * BPB * PSTRIDE; // [B*BPB] pass2 partials
constexpr int OFF_N   = OFF_LLP + B * BPB;       // [B] sum(mask)
constexpr int OFF_PAR = OFF_N + B;               // [B*32] per-b params: k*8+{alpha,cst,mu0..2,iv0..2}
// fallback-path extras
constexpr int OFF_ALPHA = OFF_PAR + B * 32;      // [B*K]
constexpr int OFF_MU    = OFF_ALPHA + B * K;     // [B*K*M]
constexpr int OFF_IV    = OFF_MU + B * K * M;    // [B*K*M]
constexpr int OFF_CST   = OFF_IV + B * K * M;    // [B*K]

__device__ __forceinline__ float wave_reduce(float v) {
    #pragma unroll
    for (int off = 32; off > 0; off >>= 1) v += __shfl_down(v, off, 64);
    return v;
}

// ---------------------------------------------------------------- fused (coop launch, hand-rolled per-b barrier)
__global__ __launch_bounds__(THREADS, 4) void fused_kernel(
    const float* __restrict__ pred, const float* __restrict__ xin,
    const int* __restrict__ heart, int* __restrict__ hdr,
    float* __restrict__ wsf, float* __restrict__ out) {
    __shared__ float xs[M][PXB];       // 24 KB
    __shared__ float msk[PXB];         // 8 KB
    __shared__ float red[WAVES * NVALS];
    __shared__ float par[K * 8];
    __shared__ int sflag;

    const int b  = blockIdx.x / BPB;
    const int cb = blockIdx.x % BPB;
    const int tid = threadIdx.x;
    int* cnt1 = hdr;           // [B]
    int* cnt2 = hdr + 32;      // [1]
    int* flg  = hdr + 40;      // [B]

    // ---- pass 1: sweep globals, stash xin+mask in LDS, block-reduce 29 partials
    float nacc = 0.0f;
    float Wk[K] = {};
    float Pa[K][M] = {};
    float Qa[K][M] = {};

    #pragma unroll
    for (int it = 0; it < CHUNKS; ++it) {
        const int li = (it * THREADS + tid) * 4;
        const int p0 = cb * PXB + li;

        const int4 h4 = *(const int4*)(heart + b * NPIX + p0);
        float mk[4];
        mk[0] = (h4.x == 1) ? 1.0f : 0.0f;
        mk[1] = (h4.y == 1) ? 1.0f : 0.0f;
        mk[2] = (h4.z == 1) ? 1.0f : 0.0f;
        mk[3] = (h4.w == 1) ? 1.0f : 0.0f;
        *(float4*)&msk[li] = make_float4(mk[0], mk[1], mk[2], mk[3]);
        nacc += (mk[0] + mk[1]) + (mk[2] + mk[3]);

        float xv[M][4];
        #pragma unroll
        for (int m = 0; m < M; ++m) {
            float4 t = *(const float4*)(xin + (b * M + m) * NPIX + p0);
            *(float4*)&xs[m][li] = t;
            xv[m][0] = t.x; xv[m][1] = t.y; xv[m][2] = t.z; xv[m][3] = t.w;
        }

        #pragma unroll
        for (int k = 0; k < K; ++k) {
            float4 pr = *(const float4*)(pred + (b * K + k) * NPIX + p0);
            float pm[4];
            pm[0] = pr.x * mk[0]; pm[1] = pr.y * mk[1];
            pm[2] = pr.z * mk[2]; pm[3] = pr.w * mk[3];
            Wk[k] += (pm[0] + pm[1]) + (pm[2] + pm[3]);
            #pragma unroll
            for (int m = 0; m < M; ++m) {
                #pragma unroll
                for (int j = 0; j < 4; ++j) {
                    float px = pm[j] * xv[m][j];
                    Pa[k][m] += px;
                    Qa[k][m] += px * xv[m][j];
                }
            }
        }
    }

    float vals[NVALS];
    vals[0] = nacc;
    #pragma unroll
    for (int k = 0; k < K; ++k) vals[1 + k] = Wk[k];
    #pragma unroll
    for (int k = 0; k < K; ++k)
        #pragma unroll
        for (int m = 0; m < M; ++m) {
            vals[1 + K + k * M + m]         = Pa[k][m];
            vals[1 + K + K * M + k * M + m] = Qa[k][m];
        }
    #pragma unroll
    for (int i = 0; i < NVALS; ++i) vals[i] = wave_reduce(vals[i]);
    const int wave = tid >> 6;
    if ((tid & 63) == 0) {
        #pragma unroll
        for (int i = 0; i < NVALS; ++i) red[wave * NVALS + i] = vals[i];
    }
    __syncthreads();
    if (tid < NVALS) {
        float s = red[tid];
        #pragma unroll
        for (int w = 1; w < WAVES; ++w) s += red[w * NVALS + tid];
        wsf[OFF_P1 + (b * BPB + cb) * PSTRIDE + tid] = s;
    }
    __syncthreads();   // drains vmem: partial row globally visible before arrive

    // ---- per-b arrive: last block computes params, others spin on flag (~32-way only)
    if (tid == 0) {
        __threadfence();
        sflag = (atomicAdd(&cnt1[b], 1) == BPB - 1) ? 1 : 0;
    }
    __syncthreads();
    const bool isLast = (sflag != 0);

    if (isLast) {
        if (tid < K) {
            const int k = tid;
            float n = 0.0f, W = 0.0f, P[M] = {}, Q[M] = {};
            for (int p = 0; p < BPB; ++p) {
                const float* base = wsf + OFF_P1 + (b * BPB + p) * PSTRIDE;
                n += base[0];
                W += base[1 + k];
                #pragma unroll
                for (int m = 0; m < M; ++m) {
                    P[m] += base[1 + K + k * M + m];
                    Q[m] += base[1 + K + K * M + k * M + m];
                }
            }
            const float s = W + EPSF;
            float* pb = wsf + OFF_PAR + b * 32 + k * 8;
            pb[0] = W / n;
            float cst = 0.0f;
            #pragma unroll
            for (int m = 0; m < M; ++m) {
                const float mu = P[m] / s;
                const float var = (Q[m] - 2.0f * mu * P[m] + mu * mu * W) / s + EPSF;
                pb[2 + m] = mu;
                pb[5 + m] = 0.5f / var;
                cst -= 0.5f * logf(6.2831853071795864f * var);
            }
            pb[1] = cst;
            if (k == 0) wsf[OFF_N + b] = n;
        }
        __syncthreads();   // drain param stores
        if (tid == 0) {
            __threadfence();
            __hip_atomic_store(&flg[b], 1, __ATOMIC_RELEASE, __HIP_MEMORY_SCOPE_AGENT);
        }
    } else {
        if (tid == 0) {
            while (__hip_atomic_load(&flg[b], __ATOMIC_ACQUIRE, __HIP_MEMORY_SCOPE_AGENT) == 0) {
                __builtin_amdgcn_s_sleep(8);
            }
        }
        __syncthreads();
    }
    __threadfence();   // acquire: invalidate caches so param reads are fresh
    if (tid < K * 8) par[tid] = wsf[OFF_PAR + b * 32 + tid];
    __syncthreads();

    // ---- pass 2: entirely from LDS
    float alpha[K], cst[K], mu[K][M], iv[K][M];
    #pragma unroll
    for (int k = 0; k < K; ++k) {
        alpha[k] = par[k * 8 + 0];
        cst[k]   = par[k * 8 + 1];
        #pragma unroll
        for (int m = 0; m < M; ++m) {
            mu[k][m] = par[k * 8 + 2 + m];
            iv[k][m] = par[k * 8 + 5 + m];
        }
    }

    float acc = 0.0f;
    #pragma unroll
    for (int it = 0; it < CHUNKS; ++it) {
        const int li = (it * THREADS + tid) * 4;
        const float4 mk4 = *(const float4*)&msk[li];
        const float mk[4] = {mk4.x, mk4.y, mk4.z, mk4.w};
        float xv[M][4];
        #pragma unroll
        for (int m = 0; m < M; ++m) {
            float4 t = *(const float4*)&xs[m][li];
            xv[m][0] = t.x; xv[m][1] = t.y; xv[m][2] = t.z; xv[m][3] = t.w;
        }
        #pragma unroll
        for (int j = 0; j < 4; ++j) {
            float mix = EPSF;
            #pragma unroll
            for (int k = 0; k < K; ++k) {
                float lp = cst[k];
                #pragma unroll
                for (int m = 0; m < M; ++m) {
                    float d = xv[m][j] - mu[k][m];
                    lp -= d * d * iv[k][m];
                }
                mix += alpha[k] * __expf(lp);
            }
            acc += mk[j] * __logf(mix);
        }
    }

    __syncthreads();          // red[] reuse
    acc = wave_reduce(acc);
    if ((tid & 63) == 0) red[wave] = acc;
    __syncthreads();
    if (tid == 0) {
        float s2 = red[0];
        #pragma unroll
        for (int w = 1; w < WAVES; ++w) s2 += red[w];
        wsf[OFF_LLP + b * BPB + cb] = s2;
    }
    __syncthreads();   // drain ll-partial store

    // ---- done-count: 1024th block does the final scalar (no one waits)
    if (tid == 0) {
        __threadfence();
        sflag = (atomicAdd(cnt2, 1) == B * BPB - 1) ? 1 : 0;
    }
    __syncthreads();
    if (sflag) {
        __threadfence();
        if (tid < 64) {
            float val = 0.0f;
            if (tid < B) {
                float s = 0.0f;
                for (int p = 0; p < BPB; ++p) s += wsf[OFF_LLP + tid * BPB + p];
                val = -s / wsf[OFF_N + tid];
            }
            val = wave_reduce(val);
            if (tid == 0) out[0] = val * (1.0f / (float)B);
        }
    }
}

// ---------------------------------------------------------------- fallback (R3 path)
__global__ __launch_bounds__(THREADS) void pass1_kernel(
    const float* __restrict__ pred, const float* __restrict__ xin,
    const int* __restrict__ heart, float* __restrict__ wsf) {
    const int b  = blockIdx.x / BPB;
    const int cb = blockIdx.x % BPB;
    float nacc = 0.0f;
    float Wk[K] = {};
    float Pa[K][M] = {};
    float Qa[K][M] = {};
    #pragma unroll
    for (int it = 0; it < CHUNKS; ++it) {
        const int p0 = cb * PXB + (it * THREADS + threadIdx.x) * 4;
        const int4 h4 = *(const int4*)(heart + b * NPIX + p0);
        float mk[4];
        mk[0] = (h4.x == 1) ? 1.0f : 0.0f;
        mk[1] = (h4.y == 1) ? 1.0f : 0.0f;
        mk[2] = (h4.z == 1) ? 1.0f : 0.0f;
        mk[3] = (h4.w == 1) ? 1.0f : 0.0f;
        nacc += (mk[0] + mk[1]) + (mk[2] + mk[3]);
        float xv[M][4];
        #pragma unroll
        for (int m = 0; m < M; ++m) {
            float4 t = *(const float4*)(xin + (b * M + m) * NPIX + p0);
            xv[m][0] = t.x; xv[m][1] = t.y; xv[m][2] = t.z; xv[m][3] = t.w;
        }
        #pragma unroll
        for (int k = 0; k < K; ++k) {
            float4 pr = *(const float4*)(pred + (b * K + k) * NPIX + p0);
            float pm[4];
            pm[0] = pr.x * mk[0]; pm[1] = pr.y * mk[1];
            pm[2] = pr.z * mk[2]; pm[3] = pr.w * mk[3];
            Wk[k] += (pm[0] + pm[1]) + (pm[2] + pm[3]);
            #pragma unroll
            for (int m = 0; m < M; ++m)
                #pragma unroll
                for (int j = 0; j < 4; ++j) {
                    float px = pm[j] * xv[m][j];
                    Pa[k][m] += px;
                    Qa[k][m] += px * xv[m][j];
                }
        }
    }
    float vals[NVALS];
    vals[0] = nacc;
    #pragma unroll
    for (int k = 0; k < K; ++k) vals[1 + k] = Wk[k];
    #pragma unroll
    for (int k = 0; k < K; ++k)
        #pragma unroll
        for (int m = 0; m < M; ++m) {
            vals[1 + K + k * M + m]         = Pa[k][m];
            vals[1 + K + K * M + k * M + m] = Qa[k][m];
        }
    __shared__ float red[WAVES * NVALS];
    #pragma unroll
    for (int i = 0; i < NVALS; ++i) vals[i] = wave_reduce(vals[i]);
    const int wave = threadIdx.x >> 6;
    if ((threadIdx.x & 63) == 0) {
        #pragma unroll
        for (int i = 0; i < NVALS; ++i) red[wave * NVALS + i] = vals[i];
    }
    __syncthreads();
    if (threadIdx.x < NVALS) {
        float s = red[threadIdx.x];
        #pragma unroll
        for (int w = 1; w < WAVES; ++w) s += red[w * NVALS + threadIdx.x];
        wsf[OFF_P1 + (b * BPB + cb) * PSTRIDE + threadIdx.x] = s;
    }
}

__global__ __launch_bounds__(B * K) void params_kernel(float* __restrict__ wsf) {
    const int t = threadIdx.x;
    const int b = t / K;
    const int k = t % K;
    float n = 0.0f, W = 0.0f, P[M] = {}, Q[M] = {};
    for (int p = 0; p < BPB; ++p) {
        const float* base = wsf + OFF_P1 + (b * BPB + p) * PSTRIDE;
        n += base[0];
        W += base[1 + k];
        #pragma unroll
        for (int m = 0; m < M; ++m) {
            P[m] += base[1 + K + k * M + m];
            Q[m] += base[1 + K + K * M + k * M + m];
        }
    }
    const float s = W + EPSF;
    wsf[OFF_ALPHA + t] = W / n;
    if (k == 0) wsf[OFF_N + b] = n;
    float cst = 0.0f;
    #pragma unroll
    for (int m = 0; m < M; ++m) {
        const float mu = P[m] / s;
        const float var = (Q[m] - 2.0f * mu * P[m] + mu * mu * W) / s + EPSF;
        wsf[OFF_MU + t * M + m] = mu;
        wsf[OFF_IV + t * M + m] = 0.5f / var;
        cst -= 0.5f * logf(6.2831853071795864f * var);
    }
    wsf[OFF_CST + t] = cst;
}

__global__ __launch_bounds__(THREADS) void pass2_kernel(
    const float* __restrict__ xin, const int* __restrict__ heart,
    float* __restrict__ wsf) {
    const int b  = blockIdx.x / BPB;
    const int cb = blockIdx.x % BPB;
    float alpha[K], cst[K], mu[K][M], iv[K][M];
    #pragma unroll
    for (int k = 0; k < K; ++k) {
        alpha[k] = wsf[OFF_ALPHA + b * K + k];
        cst[k]   = wsf[OFF_CST + b * K + k];
        #pragma unroll
        for (int m = 0; m < M; ++m) {
            mu[k][m] = wsf[OFF_MU + (b * K + k) * M + m];
            iv[k][m] = wsf[OFF_IV + (b * K + k) * M + m];
        }
    }
    float acc = 0.0f;
    #pragma unroll
    for (int it = 0; it < CHUNKS; ++it) {
        const int p0 = cb * PXB + (it * THREADS + threadIdx.x) * 4;
        const int4 h4 = *(const int4*)(heart + b * NPIX + p0);
        int hv[4] = {h4.x, h4.y, h4.z, h4.w};
        float xv[M][4];
        #pragma unroll
        for (int m = 0; m < M; ++m) {
            float4 t = *(const float4*)(xin + (b * M + m) * NPIX + p0);
            xv[m][0] = t.x; xv[m][1] = t.y; xv[m][2] = t.z; xv[m][3] = t.w;
        }
        #pragma unroll
        for (int j = 0; j < 4; ++j) {
            float mix = EPSF;
            #pragma unroll
            for (int k = 0; k < K; ++k) {
                float lp = cst[k];
                #pragma unroll
                for (int m = 0; m < M; ++m) {
                    float d = xv[m][j] - mu[k][m];
                    lp -= d * d * iv[k][m];
                }
                mix += alpha[k] * __expf(lp);
            }
            acc += ((hv[j] == 1) ? 1.0f : 0.0f) * __logf(mix);
        }
    }
    __shared__ float red[WAVES];
    acc = wave_reduce(acc);
    const int wave = threadIdx.x >> 6;
    if ((threadIdx.x & 63) == 0) red[wave] = acc;
    __syncthreads();
    if (threadIdx.x == 0) {
        float s = red[0];
        #pragma unroll
        for (int w = 1; w < WAVES; ++w) s += red[w];
        wsf[OFF_LLP + b * BPB + cb] = s;
    }
}

__global__ __launch_bounds__(64) void final_kernel(const float* __restrict__ wsf,
                                                   float* __restrict__ out) {
    const int t = threadIdx.x;
    float val = 0.0f;
    if (t < B) {
        float s = 0.0f;
        for (int p = 0; p < BPB; ++p) s += wsf[OFF_LLP + t * BPB + p];
        val = -s / wsf[OFF_N + t];
    }
    val = wave_reduce(val);
    if (t == 0) out[0] = val * (1.0f / (float)B);
}

extern "C" void kernel_launch(void* const* d_in, const int* in_sizes, int n_in,
                              void* d_out, int out_size, void* d_ws, size_t ws_size,
                              hipStream_t stream) {
    const float* pred  = (const float*)d_in[0];
    const float* xin   = (const float*)d_in[1];
    const int*   heart = (const int*)d_in[2];
    float* out = (float*)d_out;
    int*   hdr = (int*)d_ws;
    float* wsf = (float*)((char*)d_ws + HDR_BYTES);

    hipMemsetAsync(d_ws, 0, HDR_BYTES, stream);   // zero counters/flags

    void* args[] = {(void*)&pred, (void*)&xin, (void*)&heart,
                    (void*)&hdr, (void*)&wsf, (void*)&out};
    hipError_t e = hipLaunchCooperativeKernel((const void*)fused_kernel,
                                              dim3(B * BPB), dim3(THREADS),
                                              args, 0, stream);
    if (e != hipSuccess) {
        (void)hipGetLastError();  // clear sticky error; known-good 4-kernel path
        pass1_kernel<<<B * BPB, THREADS, 0, stream>>>(pred, xin, heart, wsf);
        params_kernel<<<1, B * K, 0, stream>>>(wsf);
        pass2_kernel<<<B * BPB, THREADS, 0, stream>>>(xin, heart, wsf);
        final_kernel<<<1, 64, 0, stream>>>(wsf, out);
    }
}

// Round 6
// 163.304 us; speedup vs baseline: 2.5982x; 1.8599x over previous
//
#include <hip/hip_runtime.h>

#define EPSF 1e-10f
#define SCOPE_AGENT __HIP_MEMORY_SCOPE_AGENT

constexpr int B = 32, K = 4, M = 3;
constexpr int NPIX = 256 * 256;
constexpr int BPB = 32;            // blocks per b -> 1024 blocks = exactly 4/CU co-resident
constexpr int THREADS = 256;
constexpr int WAVES = THREADS / 64;
constexpr int PXB = NPIX / BPB;    // 2048 px per block
constexpr int CHUNKS = PXB / (THREADS * 4);  // 2
constexpr int NVALS = 1 + K + 2 * K * M;     // 29
constexpr int PSTRIDE = 32;

// ---- ws layout: 512-byte int header (counters/flags, zeroed by memset), then floats
constexpr int HDR_BYTES = 512;
constexpr int OFF_P1  = 0;                          // [B*BPB*PSTRIDE] pass1 partials
constexpr int OFF_LLP = OFF_P1 + B * BPB * PSTRIDE; // [B*BPB] pass2 partials
constexpr int OFF_N   = OFF_LLP + B * BPB;          // [B] sum(mask)
constexpr int OFF_PAR = OFF_N + B;                  // [B*32] params: k*8+{alpha,cst,mu0..2,iv0..2}
// fallback-path extras
constexpr int OFF_ALPHA = OFF_PAR + B * 32;
constexpr int OFF_MU    = OFF_ALPHA + B * K;
constexpr int OFF_IV    = OFF_MU + B * K * M;
constexpr int OFF_CST   = OFF_IV + B * K * M;

__device__ __forceinline__ float wave_reduce(float v) {
    #pragma unroll
    for (int off = 32; off > 0; off >>= 1) v += __shfl_down(v, off, 64);
    return v;
}

// per-word coherent accesses (compile to sc0/sc1-flagged global ops at the
// agent coherence point) — NO L2-wide writeback/invalidate, unlike __threadfence
__device__ __forceinline__ void st_coh(float* p, float v) {
    __hip_atomic_store(p, v, __ATOMIC_RELAXED, SCOPE_AGENT);
}
__device__ __forceinline__ float ld_coh(const float* p) {
    return __hip_atomic_load(p, __ATOMIC_RELAXED, SCOPE_AGENT);
}
__device__ __forceinline__ void waitcnt0() {
    asm volatile("s_waitcnt vmcnt(0)" ::: "memory");  // drain stores; compiler barrier
}

// ---------------------------------------------------------------- fused, fence-free
__global__ __launch_bounds__(THREADS, 4) void fused_kernel(
    const float* __restrict__ pred, const float* __restrict__ xin,
    const int* __restrict__ heart, int* __restrict__ hdr,
    float* __restrict__ wsf, float* __restrict__ out) {
    __shared__ float xs[M][PXB];       // 24 KB
    __shared__ float msk[PXB];         // 8 KB
    __shared__ float red[WAVES * NVALS];
    __shared__ float par[K * 8];
    __shared__ int sflag;

    const int b  = blockIdx.x / BPB;
    const int cb = blockIdx.x % BPB;
    const int tid = threadIdx.x;
    int* cnt1 = hdr;           // [B]  arrive counters
    int* cnt2 = hdr + 32;      // [1]  done counter
    int* flg  = hdr + 40;      // [B]  param-ready flags

    // ---- pass 1: sweep globals, stash xin+mask in LDS, block-reduce 29 partials
    float nacc = 0.0f;
    float Wk[K] = {};
    float Pa[K][M] = {};
    float Qa[K][M] = {};

    #pragma unroll
    for (int it = 0; it < CHUNKS; ++it) {
        const int li = (it * THREADS + tid) * 4;
        const int p0 = cb * PXB + li;

        const int4 h4 = *(const int4*)(heart + b * NPIX + p0);
        float mk[4];
        mk[0] = (h4.x == 1) ? 1.0f : 0.0f;
        mk[1] = (h4.y == 1) ? 1.0f : 0.0f;
        mk[2] = (h4.z == 1) ? 1.0f : 0.0f;
        mk[3] = (h4.w == 1) ? 1.0f : 0.0f;
        *(float4*)&msk[li] = make_float4(mk[0], mk[1], mk[2], mk[3]);
        nacc += (mk[0] + mk[1]) + (mk[2] + mk[3]);

        float xv[M][4];
        #pragma unroll
        for (int m = 0; m < M; ++m) {
            float4 t = *(const float4*)(xin + (b * M + m) * NPIX + p0);
            *(float4*)&xs[m][li] = t;
            xv[m][0] = t.x; xv[m][1] = t.y; xv[m][2] = t.z; xv[m][3] = t.w;
        }

        #pragma unroll
        for (int k = 0; k < K; ++k) {
            float4 pr = *(const float4*)(pred + (b * K + k) * NPIX + p0);
            float pm[4];
            pm[0] = pr.x * mk[0]; pm[1] = pr.y * mk[1];
            pm[2] = pr.z * mk[2]; pm[3] = pr.w * mk[3];
            Wk[k] += (pm[0] + pm[1]) + (pm[2] + pm[3]);
            #pragma unroll
            for (int m = 0; m < M; ++m) {
                #pragma unroll
                for (int j = 0; j < 4; ++j) {
                    float px = pm[j] * xv[m][j];
                    Pa[k][m] += px;
                    Qa[k][m] += px * xv[m][j];
                }
            }
        }
    }

    float vals[NVALS];
    vals[0] = nacc;
    #pragma unroll
    for (int k = 0; k < K; ++k) vals[1 + k] = Wk[k];
    #pragma unroll
    for (int k = 0; k < K; ++k)
        #pragma unroll
        for (int m = 0; m < M; ++m) {
            vals[1 + K + k * M + m]         = Pa[k][m];
            vals[1 + K + K * M + k * M + m] = Qa[k][m];
        }
    #pragma unroll
    for (int i = 0; i < NVALS; ++i) vals[i] = wave_reduce(vals[i]);
    const int wave = tid >> 6;
    if ((tid & 63) == 0) {
        #pragma unroll
        for (int i = 0; i < NVALS; ++i) red[wave * NVALS + i] = vals[i];
    }
    __syncthreads();
    if (tid < NVALS) {
        float s = red[tid];
        #pragma unroll
        for (int w = 1; w < WAVES; ++w) s += red[w * NVALS + tid];
        st_coh(&wsf[OFF_P1 + (b * BPB + cb) * PSTRIDE + tid], s);  // coherent store
        waitcnt0();                                                // store globally visible
    }
    __syncthreads();

    // ---- per-b arrive: last block computes params, others poll flag (coherent words only)
    if (tid == 0) {
        int prev = __hip_atomic_fetch_add(&cnt1[b], 1, __ATOMIC_RELAXED, SCOPE_AGENT);
        sflag = (prev == BPB - 1) ? 1 : 0;
    }
    __syncthreads();
    const bool isLast = (sflag != 0);

    if (isLast) {
        if (tid < K) {
            const int k = tid;
            float n = 0.0f, W = 0.0f, P[M] = {}, Q[M] = {};
            for (int p = 0; p < BPB; ++p) {
                const float* base = wsf + OFF_P1 + (b * BPB + p) * PSTRIDE;
                n += ld_coh(&base[0]);
                W += ld_coh(&base[1 + k]);
                #pragma unroll
                for (int m = 0; m < M; ++m) {
                    P[m] += ld_coh(&base[1 + K + k * M + m]);
                    Q[m] += ld_coh(&base[1 + K + K * M + k * M + m]);
                }
            }
            const float s = W + EPSF;
            float* pb = wsf + OFF_PAR + b * 32 + k * 8;
            float pv[8];
            pv[0] = W / n;
            float cst = 0.0f;
            #pragma unroll
            for (int m = 0; m < M; ++m) {
                const float mu = P[m] / s;
                const float var = (Q[m] - 2.0f * mu * P[m] + mu * mu * W) / s + EPSF;
                pv[2 + m] = mu;
                pv[5 + m] = 0.5f / var;
                cst -= 0.5f * logf(6.2831853071795864f * var);
            }
            pv[1] = cst;
            #pragma unroll
            for (int j = 0; j < 8; ++j) {
                st_coh(&pb[j], pv[j]);
                par[k * 8 + j] = pv[j];     // local copy for this block's pass 2
            }
            if (k == 0) st_coh(&wsf[OFF_N + b], n);
            waitcnt0();                     // params globally visible
        }
        __syncthreads();
        if (tid == 0)
            __hip_atomic_store(&flg[b], 1, __ATOMIC_RELAXED, SCOPE_AGENT);
    } else {
        if (tid == 0) {
            while (__hip_atomic_load(&flg[b], __ATOMIC_RELAXED, SCOPE_AGENT) == 0) {
                __builtin_amdgcn_s_sleep(2);
            }
        }
        __syncthreads();
        if (tid < K * 8) par[tid] = ld_coh(&wsf[OFF_PAR + b * 32 + tid]);
    }
    __syncthreads();

    // ---- pass 2: entirely from LDS
    float alpha[K], cst[K], mu[K][M], iv[K][M];
    #pragma unroll
    for (int k = 0; k < K; ++k) {
        alpha[k] = par[k * 8 + 0];
        cst[k]   = par[k * 8 + 1];
        #pragma unroll
        for (int m = 0; m < M; ++m) {
            mu[k][m] = par[k * 8 + 2 + m];
            iv[k][m] = par[k * 8 + 5 + m];
        }
    }

    float acc = 0.0f;
    #pragma unroll
    for (int it = 0; it < CHUNKS; ++it) {
        const int li = (it * THREADS + tid) * 4;
        const float4 mk4 = *(const float4*)&msk[li];
        const float mk[4] = {mk4.x, mk4.y, mk4.z, mk4.w};
        float xv[M][4];
        #pragma unroll
        for (int m = 0; m < M; ++m) {
            float4 t = *(const float4*)&xs[m][li];
            xv[m][0] = t.x; xv[m][1] = t.y; xv[m][2] = t.z; xv[m][3] = t.w;
        }
        #pragma unroll
        for (int j = 0; j < 4; ++j) {
            float mix = EPSF;
            #pragma unroll
            for (int k = 0; k < K; ++k) {
                float lp = cst[k];
                #pragma unroll
                for (int m = 0; m < M; ++m) {
                    float d = xv[m][j] - mu[k][m];
                    lp -= d * d * iv[k][m];
                }
                mix += alpha[k] * __expf(lp);
            }
            acc += mk[j] * __logf(mix);
        }
    }

    __syncthreads();          // red[] reuse
    acc = wave_reduce(acc);
    if ((tid & 63) == 0) red[wave] = acc;
    __syncthreads();
    if (tid == 0) {
        float s2 = red[0];
        #pragma unroll
        for (int w = 1; w < WAVES; ++w) s2 += red[w];
        st_coh(&wsf[OFF_LLP + b * BPB + cb], s2);
        waitcnt0();           // ll partial visible before done-count
        sflag = (__hip_atomic_fetch_add(cnt2, 1, __ATOMIC_RELAXED, SCOPE_AGENT)
                 == B * BPB - 1) ? 1 : 0;
    }
    __syncthreads();

    // ---- 1024th block computes the final scalar (nobody waits)
    if (sflag && tid < 64) {
        float val = 0.0f;
        if (tid < B) {
            float s = 0.0f;
            for (int p = 0; p < BPB; ++p) s += ld_coh(&wsf[OFF_LLP + tid * BPB + p]);
            val = -s / ld_coh(&wsf[OFF_N + tid]);
        }
        val = wave_reduce(val);
        if (tid == 0) out[0] = val * (1.0f / (float)B);
    }
}

// ---------------------------------------------------------------- fallback (R3 path)
__global__ __launch_bounds__(THREADS) void pass1_kernel(
    const float* __restrict__ pred, const float* __restrict__ xin,
    const int* __restrict__ heart, float* __restrict__ wsf) {
    const int b  = blockIdx.x / BPB;
    const int cb = blockIdx.x % BPB;
    float nacc = 0.0f;
    float Wk[K] = {};
    float Pa[K][M] = {};
    float Qa[K][M] = {};
    #pragma unroll
    for (int it = 0; it < CHUNKS; ++it) {
        const int p0 = cb * PXB + (it * THREADS + threadIdx.x) * 4;
        const int4 h4 = *(const int4*)(heart + b * NPIX + p0);
        float mk[4];
        mk[0] = (h4.x == 1) ? 1.0f : 0.0f;
        mk[1] = (h4.y == 1) ? 1.0f : 0.0f;
        mk[2] = (h4.z == 1) ? 1.0f : 0.0f;
        mk[3] = (h4.w == 1) ? 1.0f : 0.0f;
        nacc += (mk[0] + mk[1]) + (mk[2] + mk[3]);
        float xv[M][4];
        #pragma unroll
        for (int m = 0; m < M; ++m) {
            float4 t = *(const float4*)(xin + (b * M + m) * NPIX + p0);
            xv[m][0] = t.x; xv[m][1] = t.y; xv[m][2] = t.z; xv[m][3] = t.w;
        }
        #pragma unroll
        for (int k = 0; k < K; ++k) {
            float4 pr = *(const float4*)(pred + (b * K + k) * NPIX + p0);
            float pm[4];
            pm[0] = pr.x * mk[0]; pm[1] = pr.y * mk[1];
            pm[2] = pr.z * mk[2]; pm[3] = pr.w * mk[3];
            Wk[k] += (pm[0] + pm[1]) + (pm[2] + pm[3]);
            #pragma unroll
            for (int m = 0; m < M; ++m)
                #pragma unroll
                for (int j = 0; j < 4; ++j) {
                    float px = pm[j] * xv[m][j];
                    Pa[k][m] += px;
                    Qa[k][m] += px * xv[m][j];
                }
        }
    }
    float vals[NVALS];
    vals[0] = nacc;
    #pragma unroll
    for (int k = 0; k < K; ++k) vals[1 + k] = Wk[k];
    #pragma unroll
    for (int k = 0; k < K; ++k)
        #pragma unroll
        for (int m = 0; m < M; ++m) {
            vals[1 + K + k * M + m]         = Pa[k][m];
            vals[1 + K + K * M + k * M + m] = Qa[k][m];
        }
    __shared__ float red[WAVES * NVALS];
    #pragma unroll
    for (int i = 0; i < NVALS; ++i) vals[i] = wave_reduce(vals[i]);
    const int wave = threadIdx.x >> 6;
    if ((threadIdx.x & 63) == 0) {
        #pragma unroll
        for (int i = 0; i < NVALS; ++i) red[wave * NVALS + i] = vals[i];
    }
    __syncthreads();
    if (threadIdx.x < NVALS) {
        float s = red[threadIdx.x];
        #pragma unroll
        for (int w = 1; w < WAVES; ++w) s += red[w * NVALS + threadIdx.x];
        wsf[OFF_P1 + (b * BPB + cb) * PSTRIDE + threadIdx.x] = s;
    }
}

__global__ __launch_bounds__(B * K) void params_kernel(float* __restrict__ wsf) {
    const int t = threadIdx.x;
    const int b = t / K;
    const int k = t % K;
    float n = 0.0f, W = 0.0f, P[M] = {}, Q[M] = {};
    for (int p = 0; p < BPB; ++p) {
        const float* base = wsf + OFF_P1 + (b * BPB + p) * PSTRIDE;
        n += base[0];
        W += base[1 + k];
        #pragma unroll
        for (int m = 0; m < M; ++m) {
            P[m] += base[1 + K + k * M + m];
            Q[m] += base[1 + K + K * M + k * M + m];
        }
    }
    const float s = W + EPSF;
    wsf[OFF_ALPHA + t] = W / n;
    if (k == 0) wsf[OFF_N + b] = n;
    float cst = 0.0f;
    #pragma unroll
    for (int m = 0; m < M; ++m) {
        const float mu = P[m] / s;
        const float var = (Q[m] - 2.0f * mu * P[m] + mu * mu * W) / s + EPSF;
        wsf[OFF_MU + t * M + m] = mu;
        wsf[OFF_IV + t * M + m] = 0.5f / var;
        cst -= 0.5f * logf(6.2831853071795864f * var);
    }
    wsf[OFF_CST + t] = cst;
}

__global__ __launch_bounds__(THREADS) void pass2_kernel(
    const float* __restrict__ xin, const int* __restrict__ heart,
    float* __restrict__ wsf) {
    const int b  = blockIdx.x / BPB;
    const int cb = blockIdx.x % BPB;
    float alpha[K], cst[K], mu[K][M], iv[K][M];
    #pragma unroll
    for (int k = 0; k < K; ++k) {
        alpha[k] = wsf[OFF_ALPHA + b * K + k];
        cst[k]   = wsf[OFF_CST + b * K + k];
        #pragma unroll
        for (int m = 0; m < M; ++m) {
            mu[k][m] = wsf[OFF_MU + (b * K + k) * M + m];
            iv[k][m] = wsf[OFF_IV + (b * K + k) * M + m];
        }
    }
    float acc = 0.0f;
    #pragma unroll
    for (int it = 0; it < CHUNKS; ++it) {
        const int p0 = cb * PXB + (it * THREADS + threadIdx.x) * 4;
        const int4 h4 = *(const int4*)(heart + b * NPIX + p0);
        int hv[4] = {h4.x, h4.y, h4.z, h4.w};
        float xv[M][4];
        #pragma unroll
        for (int m = 0; m < M; ++m) {
            float4 t = *(const float4*)(xin + (b * M + m) * NPIX + p0);
            xv[m][0] = t.x; xv[m][1] = t.y; xv[m][2] = t.z; xv[m][3] = t.w;
        }
        #pragma unroll
        for (int j = 0; j < 4; ++j) {
            float mix = EPSF;
            #pragma unroll
            for (int k = 0; k < K; ++k) {
                float lp = cst[k];
                #pragma unroll
                for (int m = 0; m < M; ++m) {
                    float d = xv[m][j] - mu[k][m];
                    lp -= d * d * iv[k][m];
                }
                mix += alpha[k] * __expf(lp);
            }
            acc += ((hv[j] == 1) ? 1.0f : 0.0f) * __logf(mix);
        }
    }
    __shared__ float red[WAVES];
    acc = wave_reduce(acc);
    const int wave = threadIdx.x >> 6;
    if ((threadIdx.x & 63) == 0) red[wave] = acc;
    __syncthreads();
    if (threadIdx.x == 0) {
        float s = red[0];
        #pragma unroll
        for (int w = 1; w < WAVES; ++w) s += red[w];
        wsf[OFF_LLP + b * BPB + cb] = s;
    }
}

__global__ __launch_bounds__(64) void final_kernel(const float* __restrict__ wsf,
                                                   float* __restrict__ out) {
    const int t = threadIdx.x;
    float val = 0.0f;
    if (t < B) {
        float s = 0.0f;
        for (int p = 0; p < BPB; ++p) s += wsf[OFF_LLP + t * BPB + p];
        val = -s / wsf[OFF_N + t];
    }
    val = wave_reduce(val);
    if (t == 0) out[0] = val * (1.0f / (float)B);
}

extern "C" void kernel_launch(void* const* d_in, const int* in_sizes, int n_in,
                              void* d_out, int out_size, void* d_ws, size_t ws_size,
                              hipStream_t stream) {
    const float* pred  = (const float*)d_in[0];
    const float* xin   = (const float*)d_in[1];
    const int*   heart = (const int*)d_in[2];
    float* out = (float*)d_out;
    int*   hdr = (int*)d_ws;
    float* wsf = (float*)((char*)d_ws + HDR_BYTES);

    hipMemsetAsync(d_ws, 0, HDR_BYTES, stream);   // zero counters/flags

    void* args[] = {(void*)&pred, (void*)&xin, (void*)&heart,
                    (void*)&hdr, (void*)&wsf, (void*)&out};
    hipError_t e = hipLaunchCooperativeKernel((const void*)fused_kernel,
                                              dim3(B * BPB), dim3(THREADS),
                                              args, 0, stream);
    if (e != hipSuccess) {
        (void)hipGetLastError();  // clear sticky error; known-good 4-kernel path
        pass1_kernel<<<B * BPB, THREADS, 0, stream>>>(pred, xin, heart, wsf);
        params_kernel<<<1, B * K, 0, stream>>>(wsf);
        pass2_kernel<<<B * BPB, THREADS, 0, stream>>>(xin, heart, wsf);
        final_kernel<<<1, 64, 0, stream>>>(wsf, out);
    }
}